// Round 7
// baseline (480.426 us; speedup 1.0000x reference)
//
#include <hip/hip_runtime.h>
#include <cstdint>

#define NB 8
#define NA 100000
#define NC 80
#define TOPN 1000
#define MAXOBJ 100
#define NREG 64        // candidate sub-lists per image (atomic contention spread)
#define REGCAP 256     // entries per sub-list; 64*256 = 16384 slots per image
#define CTRSTRIDE 32   // uints between counters -> each on its own 128B line
#define SORTN 2048     // final sort size
#define MIN_SCORE 0.05f
#define NMS_THR 0.5f

// ---------------- K1: per-anchor max/argmax + prefilter append ----------------
// 4 lanes cooperate per anchor (80 classes = 20 float4; 5 float4/lane).
// Round-5 proven-fastest config: 64 anchors per 256-thread block.
__global__ __launch_bounds__(256) void k_scores(const float* __restrict__ cls,
                                                unsigned int* __restrict__ keys,
                                                int* __restrict__ clsid,
                                                unsigned long long* __restrict__ cand,
                                                unsigned int* __restrict__ n_cand) {
    const int b = blockIdx.y;
    const int t = threadIdx.x;
    const int lane = t & 63;
    const int sub = lane & 3;                    // lane within 4-lane group
    const int a = blockIdx.x * 64 + (t >> 2);    // anchor for this group
    const bool valid = (a < NA);
    const int aa = valid ? a : (NA - 1);

    const float4* p = (const float4*)(cls + ((size_t)b * NA + aa) * NC);

    float vm = -1e30f; int vi = 0x7FFFFFFF;
#pragma unroll
    for (int s = 0; s < 5; ++s) {
        float4 v = p[sub + s * 4];
        int c0 = (sub + s * 4) * 4;
        if (v.x > vm) { vm = v.x; vi = c0; }
        if (v.y > vm) { vm = v.y; vi = c0 + 1; }
        if (v.z > vm) { vm = v.z; vi = c0 + 2; }
        if (v.w > vm) { vm = v.w; vi = c0 + 3; }
    }
    // cross-lane reduce within the 4-lane group: larger max; tie -> smaller idx
#pragma unroll
    for (int d = 1; d < 4; d <<= 1) {
        float ovm = __shfl_xor(vm, d);
        int ovi = __shfl_xor(vi, d);
        if (ovm > vm || (ovm == vm && ovi < vi)) { vm = ovm; vi = ovi; }
    }

    unsigned int key = (vm > MIN_SCORE) ? __float_as_uint(vm) : 0u;
    if (valid && sub == 0) {
        size_t o = (size_t)b * NA + a;
        keys[o] = key;
        clsid[o] = vi;
    }

    // prefilter: append anchors with score >= 0.999 (expected ~7.7k/image)
    const unsigned int T0 = __float_as_uint(0.999f);
    bool w = valid && (sub == 0) && (key >= T0);
    unsigned long long m = __ballot(w);
    if (m) {
        const int r = blockIdx.x & (NREG - 1);
        unsigned int* ctr = n_cand + (size_t)((b << 6) | r) * CTRSTRIDE;
        unsigned long long* creg = cand + ((size_t)((b << 6) | r)) * REGCAP;
        int leader = (int)__builtin_ctzll(m);
        unsigned int bs = 0;
        if (lane == leader) bs = atomicAdd(ctr, (unsigned int)__popcll(m));
        bs = __shfl(bs, leader);
        unsigned int pos = bs + (unsigned int)__popcll(m & ((1ull << lane) - 1ull));
        if (w && pos < REGCAP)
            creg[pos] =
                ((unsigned long long)key << 32) |
                (unsigned long long)(0xFFFFFFFFu - (unsigned int)a);
    }
}

// wave-aggregated LDS histogram add (for concentrated bins)
__device__ inline void wave_agg_hist(unsigned int* lh, int bin, bool pred) {
    unsigned long long active = __ballot(pred);
    const int lane = threadIdx.x & 63;
    while (active) {
        int leader = (int)__builtin_ctzll(active);
        int lbin = __shfl(bin, leader);
        unsigned long long mask = __ballot(pred && (bin == lbin));
        if (lane == leader) atomicAdd(&lh[lbin], (unsigned int)__popcll(mask));
        active &= ~mask;
    }
}

// one wave: suffix-scan threshold search over LDS histogram
__device__ inline void top_threshold(const unsigned int* lh, int nbins, int minbin,
                                     unsigned int rank, int* out_bin, unsigned int* out_above) {
    const int lane = threadIdx.x;  // caller guarantees tid < 64
    const int chunk = nbins >> 6;
    const int hi = nbins - 1 - lane * chunk;
    const int lo = hi - chunk + 1;
    unsigned int s = 0;
    for (int i = hi; i >= lo; --i)
        if (i >= minbin) s += lh[i];
    unsigned int incl = s;
    for (int d = 1; d < 64; d <<= 1) {
        unsigned int o = __shfl_up(incl, d);
        if (lane >= d) incl += o;
    }
    unsigned int pre = incl - s;
    bool hit = (pre < rank) && (incl >= rank);
    unsigned long long m = __ballot(hit);
    if (m == 0ull) {
        if (lane == 0) { *out_bin = -1; *out_above = 0; }
        return;
    }
    if (hit) {
        unsigned int cum = pre;
        int fb = -1;
        for (int i = hi; i >= lo; --i) {
            if (i < minbin) break;
            unsigned int c = lh[i];
            if (cum + c >= rank) { fb = i; break; }
            cum += c;
        }
        *out_bin = fb;
        *out_above = cum;
    }
}

// ---------------- K2a: exact top-1000 select + sort + decode -> workspace ----------------
// Fast path: radix over the 64x256-slot candidate space (L2-hot). Slow path
// (candidate underflow / region overflow, never on this bench): radix over keys[].
// Writes sorted (desc score, tie: anchor asc) decoded top-1000 to ws arrays.
__global__ __launch_bounds__(1024) void k_topk(
    const unsigned int* __restrict__ keys, const int* __restrict__ clsid,
    const unsigned long long* __restrict__ cand, const unsigned int* __restrict__ n_cand,
    const float* __restrict__ reg, const float* __restrict__ anch,
    float* __restrict__ sscore, float* __restrict__ sclass, float4* __restrict__ sbox) {
    __shared__ unsigned int lh[2048];
    __shared__ unsigned long long sk[SORTN];
    __shared__ unsigned int s_rc[NREG];
    __shared__ int s_bin;
    __shared__ unsigned int s_above;
    __shared__ unsigned int s_cnt;
    __shared__ unsigned int s_tot;
    __shared__ int s_ovf;

    const int b = blockIdx.x;
    const int tid = threadIdx.x;
    const int lane = tid & 63;
    const unsigned int* kb = keys + (size_t)b * NA;
    const unsigned long long* cb = cand + ((size_t)b << 6) * REGCAP;

    // load 64 region counts; wave 0 computes total + overflow
    if (tid < NREG) {
        unsigned int c = n_cand[(size_t)((b << 6) | tid) * CTRSTRIDE];
        s_rc[tid] = c;
        unsigned int cc = min(c, (unsigned int)REGCAP);
        for (int d = 32; d; d >>= 1) cc += __shfl_down(cc, d);
        unsigned long long om = __ballot(c > REGCAP);
        if (tid == 0) { s_tot = cc; s_ovf = (om != 0ull) ? 1 : 0; }
    }
    __syncthreads();

    const bool fast = (!s_ovf) && (s_tot >= TOPN);
    const int N = fast ? (NREG * REGCAP) : NA;

// fetch one slot: key=0 if invalid
#define FETCH(i, k, e)                                                        \
    {                                                                         \
        (k) = 0u; (e) = 0ull;                                                 \
        if ((i) < N) {                                                        \
            if (fast) {                                                       \
                int rr = (i) >> 8, pp = (i) & (REGCAP - 1);                   \
                if (pp < (int)s_rc[rr]) {                                     \
                    (e) = cb[i]; (k) = (unsigned int)((e) >> 32);             \
                }                                                             \
            } else {                                                          \
                (k) = kb[i];                                                  \
                (e) = ((unsigned long long)(k) << 32) |                       \
                      (unsigned long long)(0xFFFFFFFFu - (unsigned int)(i));  \
            }                                                                 \
        }                                                                     \
    }

    // ---- radix pass 1: bins = key >> 21 (concentrated -> wave-aggregated) ----
    for (int i = tid; i < 2048; i += 1024) lh[i] = 0;
    __syncthreads();
    for (int base = 0; base < N; base += 1024) {
        int i = base + tid;
        unsigned int k; unsigned long long e;
        FETCH(i, k, e)
        (void)e;
        wave_agg_hist(lh, (int)(k >> 21), k != 0u);
    }
    __syncthreads();
    if (tid < 64) top_threshold(lh, 2048, 1, TOPN, &s_bin, &s_above);
    __syncthreads();
    const int p1 = s_bin;
    const unsigned int above1 = s_above;

    unsigned int T;
    if (p1 < 0) {
        T = 1u;  // fewer than TOPN valid: take all nonzero
    } else {
        // ---- pass 2: bits[20:10] within bin p1 (spread -> plain atomics) ----
        __syncthreads();
        for (int i = tid; i < 2048; i += 1024) lh[i] = 0;
        __syncthreads();
        for (int base = 0; base < N; base += 1024) {
            int i = base + tid;
            unsigned int k; unsigned long long e;
            FETCH(i, k, e)
            (void)e;
            if (k != 0u && (int)(k >> 21) == p1) atomicAdd(&lh[(k >> 10) & 0x7FFu], 1u);
        }
        __syncthreads();
        if (tid < 64) top_threshold(lh, 2048, 0, TOPN - above1, &s_bin, &s_above);
        __syncthreads();
        const int p2 = s_bin;
        const unsigned int above2 = above1 + s_above;
        if (p2 < 0) {
            T = 1u;
        } else if (above2 + lh[p2] <= SORTN) {
            // pass-3 skip: everything >= the (p1,p2) bin floor fits in the sort
            // buffer -> exact top-1000 still falls out of the full sort.
            T = (((unsigned int)p1 << 11) | (unsigned int)p2) << 10;
        } else {
            // ---- pass 3: low 10 bits within (p1,p2) ----
            const unsigned int pref = ((unsigned int)p1 << 11) | (unsigned int)p2;
            __syncthreads();
            for (int i = tid; i < 1024; i += 1024) lh[i] = 0;
            __syncthreads();
            for (int base = 0; base < N; base += 1024) {
                int i = base + tid;
                unsigned int k; unsigned long long e;
                FETCH(i, k, e)
                (void)e;
                if (k != 0u && (k >> 10) == pref) atomicAdd(&lh[k & 0x3FFu], 1u);
            }
            __syncthreads();
            if (tid < 64) top_threshold(lh, 1024, 0, TOPN - above2, &s_bin, &s_above);
            __syncthreads();
            T = (s_bin < 0) ? 1u : ((pref << 10) | (unsigned int)s_bin);
        }
    }
    __syncthreads();

    // ---- collect entries >= T (ballot-compacted) ----
    for (int i = tid; i < SORTN; i += 1024) sk[i] = 0ull;
    if (tid == 0) s_cnt = 0;
    __syncthreads();
    for (int base = 0; base < N; base += 1024) {
        int i = base + tid;
        unsigned int k; unsigned long long e;
        FETCH(i, k, e)
        bool w = (k >= T) && (k != 0u);
        unsigned long long m = __ballot(w);
        if (m) {
            int leader = (int)__builtin_ctzll(m);
            unsigned int bs = 0;
            if (lane == leader) bs = atomicAdd(&s_cnt, (unsigned int)__popcll(m));
            bs = __shfl(bs, leader);
            unsigned int pos = bs + (unsigned int)__popcll(m & ((1ull << lane) - 1ull));
            if (w && pos < SORTN) sk[pos] = e;
        }
    }
    __syncthreads();
#undef FETCH

    // ---- bitonic sort SORTN, descending ----
    for (int k = 2; k <= SORTN; k <<= 1)
        for (int j = k >> 1; j > 0; j >>= 1) {
            __syncthreads();
            for (int i = tid; i < SORTN; i += 1024) {
                int ixj = i ^ j;
                if (ixj > i) {
                    unsigned long long x = sk[i], y = sk[ixj];
                    bool desc = ((i & k) == 0);
                    if (desc ? (x < y) : (x > y)) { sk[i] = y; sk[ixj] = x; }
                }
            }
        }
    __syncthreads();

    // ---- decode top TOPN -> workspace (rank-ordered) ----
    const size_t wsb = (size_t)b * 1024;
    if (tid < TOPN) {
        unsigned long long e = sk[tid];
        unsigned int key = (unsigned int)(e >> 32);
        if (key != 0u) {
            int a = (int)(0xFFFFFFFFu - (unsigned int)e);
            size_t base = (size_t)b * NA + a;
            float4 r  = ((const float4*)reg)[base];
            float4 an = ((const float4*)anch)[base];
            float aw = an.z - an.x, ah = an.w - an.y;
            float acx = an.x + 0.5f * aw, acy = an.y + 0.5f * ah;
            float pw = expf(r.z) * aw, ph = expf(r.w) * ah;
            float pcx = r.x * aw + acx, pcy = r.y * ah + acy;
            float4 bx;
            bx.x = truncf(pcx - 0.5f * pw); bx.y = truncf(pcy - 0.5f * ph);
            bx.z = truncf(pcx + 0.5f * pw); bx.w = truncf(pcy + 0.5f * ph);
            sbox[wsb + tid] = bx;
            sscore[wsb + tid] = __uint_as_float(key);
            sclass[wsb + tid] = (float)clsid[base];
        } else {
            sbox[wsb + tid] = make_float4(0.f, 0.f, 0.f, 0.f);
            sscore[wsb + tid] = -1.0f;
            sclass[wsb + tid] = -1.0f;
        }
    } else if (tid < 1024) {
        sscore[wsb + tid] = -1.0f;  // pad ranks 1000..1023
    }
}

// ---------------- K2b: parallel IoU suppression masks ----------------
// One wave per rank-row i: 16 x u64 ballot mask over j in [0,1000), bit set iff
// j > i and IoU(box_i, box_j) >= 0.5. Rows with invalid score skipped (never read).
__global__ __launch_bounds__(256) void k_nmsmask(
    const float* __restrict__ sscore, const float4* __restrict__ sbox,
    unsigned long long* __restrict__ masks) {
    const int b = blockIdx.y;
    const int lane = threadIdx.x & 63;
    const int i = blockIdx.x * 4 + (threadIdx.x >> 6);
    if (i >= TOPN) return;
    const size_t wsb = (size_t)b * 1024;
    if (!(sscore[wsb + i] > MIN_SCORE)) return;  // invalid row: scan never reads it

    const float4 bi = sbox[wsb + i];
    const float ai = fmaxf((bi.z - bi.x) * (bi.w - bi.y), 1e-4f);
    unsigned long long* mrow = masks + ((size_t)b * 1024 + i) * 16;

#pragma unroll 4
    for (int c = 0; c < 16; ++c) {
        int j = c * 64 + lane;
        float4 bj = sbox[wsb + j];
        float aj = fmaxf((bj.z - bj.x) * (bj.w - bj.y), 1e-4f);
        float ix = fminf(bi.z, bj.z) - fmaxf(bi.x, bj.x);
        float iy = fminf(bi.w, bj.w) - fmaxf(bi.y, bj.y);
        float inter = fmaxf(ix, 0.0f) * fmaxf(iy, 0.0f);
        float uni = fmaxf(ai + aj - inter, 1e-4f);
        bool pred = (j > i) && (j < TOPN) && (inter / uni >= NMS_THR);
        unsigned long long m = __ballot(pred);
        if (lane == 0) mrow[c] = m;
    }
}

// ---------------- K2c: greedy scan over precomputed masks + output ----------------
// One wave per image. Suppression state = 16 per-lane u64 accumulators; per
// iteration only two ballots (no memory on the serial path); kept rows load
// their 128B mask line and write the output.
__global__ __launch_bounds__(64) void k_nmsout(
    const float* __restrict__ sscore, const float* __restrict__ sclass,
    const float4* __restrict__ sbox, const unsigned long long* __restrict__ masks,
    float* __restrict__ out) {
    const int b = blockIdx.x;
    const int lane = threadIdx.x;
    float* out_s = out + b * MAXOBJ;
    float* out_c = out + NB * MAXOBJ + b * MAXOBJ;
    float* out_b = out + 2 * NB * MAXOBJ + b * MAXOBJ * 4;

    for (int i = lane; i < MAXOBJ; i += 64) { out_s[i] = -1.0f; out_c[i] = -1.0f; }
    for (int i = lane; i < MAXOBJ * 4; i += 64) out_b[i] = 0.0f;

    const size_t wsb = (size_t)b * 1024;
    const float* ssb = sscore + wsb;
    const float* scb = sclass + wsb;
    const float4* sbb = sbox + wsb;
    const unsigned long long* mb = masks + wsb * 16;

    // validity bitmap, lane c holds chunk c (c < 16)
    unsigned long long vbits = 0ull;
    for (int c = 0; c < 16; ++c) {
        unsigned long long m = __ballot(ssb[c * 64 + lane] > MIN_SCORE);
        if (lane == c) vbits = m;
    }

    unsigned long long acc = 0ull;  // suppression accumulator, lane l covers [64l, 64l+64)
    int kc = 0;
    for (int i = 0; i < TOPN; ++i) {
        const int chunk = i >> 6;
        const unsigned long long bit = 1ull << (i & 63);
        const bool mine = (lane == chunk);
        if (__ballot(mine && ((vbits & bit) == 0ull)))
            break;  // first invalid rank: all later ranks invalid too
        bool sup = (__ballot(mine && ((acc & bit) != 0ull)) != 0ull);
        if (!sup) {
            if (lane < 16) acc |= mb[(size_t)i * 16 + lane];
            if (lane == 0) {
                out_s[kc] = ssb[i];
                out_c[kc] = scb[i];
                float4 bx = sbb[i];
                out_b[kc * 4 + 0] = bx.x; out_b[kc * 4 + 1] = bx.y;
                out_b[kc * 4 + 2] = bx.z; out_b[kc * 4 + 3] = bx.w;
            }
            ++kc;
            if (kc >= MAXOBJ) break;
        }
    }
}

extern "C" void kernel_launch(void* const* d_in, const int* in_sizes, int n_in,
                              void* d_out, int out_size, void* d_ws, size_t ws_size,
                              hipStream_t stream) {
    const float* cls  = (const float*)d_in[0];
    const float* reg  = (const float*)d_in[1];
    const float* anch = (const float*)d_in[2];
    float* out = (float*)d_out;
    char* ws = (char*)d_ws;

    unsigned int* keys = (unsigned int*)ws;                          // 3,200,000 B
    int* clsid = (int*)(ws + 3200000);                               // 3,200,000 B
    unsigned long long* cand = (unsigned long long*)(ws + 6400000);  // 8*64*256*8 = 1,048,576 B
    unsigned int* n_cand = (unsigned int*)(ws + 7448576);            // 8*64*128 = 65,536 B
    float4* sbox = (float4*)(ws + 7514112);                          // 8*1024*16 = 131,072 B
    float* sscore = (float*)(ws + 7645184);                          // 8*1024*4 = 32,768 B
    float* sclass = (float*)(ws + 7677952);                          // 8*1024*4 = 32,768 B
    unsigned long long* masks = (unsigned long long*)(ws + 7710720); // 8*1024*16*8 = 1,048,576 B

    hipMemsetAsync(n_cand, 0, (size_t)NB * NREG * CTRSTRIDE * 4, stream);

    dim3 gscore((NA + 63) / 64, NB);  // 1563 x 8, 64 anchors/block
    k_scores<<<gscore, 256, 0, stream>>>(cls, keys, clsid, cand, n_cand);
    k_topk<<<NB, 1024, 0, stream>>>(keys, clsid, cand, n_cand, reg, anch,
                                    sscore, sclass, sbox);
    dim3 gmask((TOPN + 3) / 4, NB);   // 250 x 8, 4 rows (waves) per block
    k_nmsmask<<<gmask, 256, 0, stream>>>(sscore, sbox, masks);
    k_nmsout<<<NB, 64, 0, stream>>>(sscore, sclass, sbox, masks, out);
}